// Round 2
// baseline (334.673 us; speedup 1.0000x reference)
//
#include <hip/hip_runtime.h>
#include <hip/hip_bf16.h>
#include <math.h>

#define T0 128
#define BN 256           // B*N = 8*32
#define Ff 128
#define Hh 256
#define NODE0 32768      // BN*T0
#define E0 262144        // NODE0*8
#define T1 64
#define NODE1 16384      // BN*T1
#define E1 131072
#define CAP 48           // per-node in-edge capacity; deg ~ Poisson(8), P(>48) ~ 1e-25

typedef __attribute__((ext_vector_type(8))) short bhalf8;
typedef __attribute__((ext_vector_type(4))) float floatx4;
typedef __attribute__((ext_vector_type(16))) float floatx16;

__device__ __forceinline__ unsigned short f2bf(float x) {
  union { float f; unsigned u; } v; v.f = x;
  unsigned r = v.u + 0x7fff + ((v.u >> 16) & 1);
  return (unsigned short)(r >> 16);
}
__device__ __forceinline__ float bf2f(unsigned short b) {
  union { unsigned u; float f; } v; v.u = ((unsigned)b) << 16;
  return v.f;
}
// update two running maxes from one packed int (2 bf16)
__device__ __forceinline__ void max2(float& mlo, float& mhi, int p) {
  union { unsigned u; float f; } lo, hi;
  lo.u = ((unsigned)p) << 16;
  hi.u = ((unsigned)p) & 0xffff0000u;
  mlo = fmaxf(mlo, lo.f);
  mhi = fmaxf(mhi, hi.f);
}

// ---------------- fused prep + edge-fill kernel ----------------
__global__ void k_prepfill(const float* __restrict__ data, unsigned short* __restrict__ X0b,
                           const float* __restrict__ W0, unsigned short* __restrict__ Wbot0,
                           unsigned short* __restrict__ Wd0,
                           const float* __restrict__ W1, unsigned short* __restrict__ Wbot1,
                           unsigned short* __restrict__ Wd1,
                           const float* __restrict__ Wc0, unsigned short* __restrict__ Wtb0,
                           const float* __restrict__ Wc1, unsigned short* __restrict__ Wtb1,
                           const int* __restrict__ ei0, const int* __restrict__ ei1,
                           int* __restrict__ cnt0, int* __restrict__ cnt1,
                           int* __restrict__ slot0, int* __restrict__ slot1) {
  int b = blockIdx.x;
  int tid = threadIdx.x;
  if (b < 2048) {
    int idx = b * 256 + tid;          // NODE0*16, 8 elems each
    int c8 = idx & 15;
    int r  = idx >> 4;
    int t  = r & (T0 - 1);
    int bn = r >> 7;
    const float* s = data + ((size_t)t * BN + bn) * Ff + c8 * 8;
    float4 a = *(const float4*)s;
    float4 bb = *(const float4*)(s + 4);
    unsigned short o[8];
    o[0] = f2bf(a.x); o[1] = f2bf(a.y); o[2] = f2bf(a.z); o[3] = f2bf(a.w);
    o[4] = f2bf(bb.x); o[5] = f2bf(bb.y); o[6] = f2bf(bb.z); o[7] = f2bf(bb.w);
    *(int4*)(X0b + ((size_t)(bn * T0 + t) * Ff + c8 * 8)) = *(int4*)o;
  } else if (b < 2176) {
    int idx = (b - 2048) * 256 + tid; // 32768 = 256*128
    int n = idx >> 7, k = idx & 127;
    float top = W0[(size_t)k * 256 + n];
    float bot = W0[(size_t)(128 + k) * 256 + n];
    Wbot0[idx] = f2bf(bot);
    Wd0[idx]   = f2bf(top - bot);
  } else if (b < 2432) {
    int idx = (b - 2176) * 256 + tid; // 65536 = 256*256
    int n = idx >> 8, k = idx & 255;
    float top = W1[(size_t)k * 256 + n];
    float bot = W1[(size_t)(256 + k) * 256 + n];
    Wbot1[idx] = f2bf(bot);
    Wd1[idx]   = f2bf(top - bot);
  } else if (b < 3712) {
    int idx = (b - 2432) * 256 + tid; // 5*65536
    int tap = idx >> 16, o = (idx >> 8) & 255, i = idx & 255;
    Wtb0[idx] = f2bf(Wc0[((size_t)o * 256 + i) * 5 + tap]);
  } else if (b < 4992) {
    int idx = (b - 3712) * 256 + tid;
    int tap = idx >> 16, o = (idx >> 8) & 255, i = idx & 255;
    Wtb1[idx] = f2bf(Wc1[((size_t)o * 256 + i) * 5 + tap]);
  } else {
    int e = (b - 4992) * 256 + tid;   // E0+E1 = 393216 over 1536 blocks
    if (e < E0) {
      int d = ei0[E0 + e];
      int p = atomicAdd(&cnt0[d], 1);
      if (p < CAP) slot0[(size_t)d * CAP + p] = ei0[e];
    } else {
      int e2 = e - E0;
      int d = ei1[E1 + e2];
      int p = atomicAdd(&cnt1[d], 1);
      if (p < CAP) slot1[(size_t)d * CAP + p] = ei1[e2];
    }
  }
}

// ---------------- fused dual-output MFMA GEMM (v3) ----------------
// 128x128 block, 4 waves, 2 row-tiles/wave. New this round:
//  - register prefetch: next k-tile's global loads issued before the compute
//    barrier, ds_written at the top of the next iteration (hides HBM/L3
//    latency under MFMA; the old code serialized stage->barrier->MFMA).
//  - swapped-operand MFMA (mfma(b,a)): lane then holds ONE node row with 4
//    consecutive channels per acc reg -> epilogue is 32 ushort4 stores
//    instead of 128 scalar 2B stores (4x fewer, 16B segments).
__global__ __launch_bounds__(256) void k_gemm2(const unsigned short* __restrict__ A,
                                               const unsigned short* __restrict__ Wbot,
                                               const unsigned short* __restrict__ Wd,
                                               unsigned short* __restrict__ Bm,
                                               unsigned short* __restrict__ P, int K,
                                               const float* __restrict__ bias) {
  __shared__ __align__(16) short A_lds[128 * 72];
  __shared__ __align__(16) short B0_lds[128 * 72];
  __shared__ __align__(16) short B1_lds[128 * 72];
  int tid = threadIdx.x;
  int row0 = blockIdx.x * 128;
  int col0 = blockIdx.y * 128;
  int lane = tid & 63, wv = tid >> 6;
  int m16 = lane & 15, quad = lane >> 4;
  int sr = tid >> 3, sseg = tid & 7;

  const unsigned short* Abase  = A    + (size_t)(row0 + sr) * K + sseg * 8;
  const unsigned short* B0base = Wbot + (size_t)(col0 + sr) * K + sseg * 8;
  const unsigned short* B1base = Wd   + (size_t)(col0 + sr) * K + sseg * 8;

  int4 ra[4], rb0[4], rb1[4];
#pragma unroll
  for (int i = 0; i < 4; ++i) {
    ra[i]  = *(const int4*)(Abase  + (size_t)i * 32 * K);
    rb0[i] = *(const int4*)(B0base + (size_t)i * 32 * K);
    rb1[i] = *(const int4*)(B1base + (size_t)i * 32 * K);
  }

  floatx4 accB[2][8], accP[2][8];
#pragma unroll
  for (int rt = 0; rt < 2; ++rt)
#pragma unroll
    for (int nt = 0; nt < 8; ++nt) {
      accB[rt][nt] = (floatx4){0.f, 0.f, 0.f, 0.f};
      accP[rt][nt] = (floatx4){0.f, 0.f, 0.f, 0.f};
    }

  for (int kb = 0; kb < K; kb += 64) {
    __syncthreads();
#pragma unroll
    for (int i = 0; i < 4; ++i) {
      int r = sr + i * 32;
      *(int4*)&A_lds[r * 72 + sseg * 8]  = ra[i];
      *(int4*)&B0_lds[r * 72 + sseg * 8] = rb0[i];
      *(int4*)&B1_lds[r * 72 + sseg * 8] = rb1[i];
    }
    if (kb + 64 < K) {
#pragma unroll
      for (int i = 0; i < 4; ++i) {
        ra[i]  = *(const int4*)(Abase  + (size_t)i * 32 * K + kb + 64);
        rb0[i] = *(const int4*)(B0base + (size_t)i * 32 * K + kb + 64);
        rb1[i] = *(const int4*)(B1base + (size_t)i * 32 * K + kb + 64);
      }
    }
    __syncthreads();
#pragma unroll
    for (int ks = 0; ks < 2; ++ks) {
      bhalf8 a0 = *(const bhalf8*)&A_lds[(wv * 32 + m16) * 72 + ks * 32 + quad * 8];
      bhalf8 a1 = *(const bhalf8*)&A_lds[(wv * 32 + 16 + m16) * 72 + ks * 32 + quad * 8];
#pragma unroll
      for (int nt = 0; nt < 8; ++nt) {
        bhalf8 b0 = *(const bhalf8*)&B0_lds[(nt * 16 + m16) * 72 + ks * 32 + quad * 8];
        accB[0][nt] = __builtin_amdgcn_mfma_f32_16x16x32_bf16(b0, a0, accB[0][nt], 0, 0, 0);
        accB[1][nt] = __builtin_amdgcn_mfma_f32_16x16x32_bf16(b0, a1, accB[1][nt], 0, 0, 0);
        bhalf8 b1 = *(const bhalf8*)&B1_lds[(nt * 16 + m16) * 72 + ks * 32 + quad * 8];
        accP[0][nt] = __builtin_amdgcn_mfma_f32_16x16x32_bf16(b1, a0, accP[0][nt], 0, 0, 0);
        accP[1][nt] = __builtin_amdgcn_mfma_f32_16x16x32_bf16(b1, a1, accP[1][nt], 0, 0, 0);
      }
    }
  }

  // swapped C/D layout: value = C[node=row0+wv*32+rt*16+m16][col0+nt*16+quad*4+r]
#pragma unroll
  for (int rt = 0; rt < 2; ++rt) {
    int row = row0 + wv * 32 + rt * 16 + m16;
#pragma unroll
    for (int nt = 0; nt < 8; ++nt) {
      int c = col0 + nt * 16 + quad * 4;
      float4 bv = *(const float4*)&bias[c];
      ushort4 ob, op;
      ob.x = f2bf(accB[rt][nt][0]); ob.y = f2bf(accB[rt][nt][1]);
      ob.z = f2bf(accB[rt][nt][2]); ob.w = f2bf(accB[rt][nt][3]);
      op.x = f2bf(accP[rt][nt][0] + bv.x); op.y = f2bf(accP[rt][nt][1] + bv.y);
      op.z = f2bf(accP[rt][nt][2] + bv.z); op.w = f2bf(accP[rt][nt][3] + bv.w);
      *(ushort4*)(Bm + (size_t)row * 256 + c) = ob;
      *(ushort4*)(P  + (size_t)row * 256 + c) = op;
    }
  }
}

// ---------------- segment max + fused relu epilogue (v2) ----------------
// 4 nodes/block, 1 wave/node. Lane-halves split sources: 32 lanes cover a
// 512B row with int4 (16B) loads, half h processes sources i+2j+h; final
// cross-half combine via one shfl_xor(32) pass. Gather instruction count
// halved at equal bytes-in-flight vs the 8B version.
__global__ __launch_bounds__(256) void k_maxg2(const unsigned short* __restrict__ Bm,
                                               const int* __restrict__ cnt,
                                               const int* __restrict__ slot,
                                               const unsigned short* __restrict__ P,
                                               unsigned short* __restrict__ X1) {
  int node = blockIdx.x * 4 + (threadIdx.x >> 6);
  int lane = threadIdx.x & 63;
  int half = lane >> 5, c8 = lane & 31;
  int n = cnt[node];
  if (n > CAP) n = CAP;
  const int* sl = slot + (size_t)node * CAP;
  float m[8];
#pragma unroll
  for (int e = 0; e < 8; ++e) m[e] = -INFINITY;
  for (int i = 0; i < n; i += 8) {
    int s[4];
#pragma unroll
    for (int j = 0; j < 4; ++j) {
      int idx = i + 2 * j + half;
      s[j] = sl[(idx < n) ? idx : (n - 1)];
    }
    int4 v[4];
#pragma unroll
    for (int j = 0; j < 4; ++j)
      v[j] = *(const int4*)(Bm + (size_t)s[j] * 256 + c8 * 8);
#pragma unroll
    for (int j = 0; j < 4; ++j) {
      max2(m[0], m[1], v[j].x);
      max2(m[2], m[3], v[j].y);
      max2(m[4], m[5], v[j].z);
      max2(m[6], m[7], v[j].w);
    }
  }
#pragma unroll
  for (int e = 0; e < 8; ++e) m[e] = fmaxf(m[e], __shfl_xor(m[e], 32));
  if (half == 0) {
    int4 p = *(const int4*)(P + (size_t)node * 256 + c8 * 8);
    int4 o;
    unsigned short r0, r1;
    r0 = f2bf(fmaxf(bf2f((unsigned short)(p.x & 0xffff)) + m[0], 0.f));
    r1 = f2bf(fmaxf(bf2f((unsigned short)((unsigned)p.x >> 16)) + m[1], 0.f));
    o.x = (int)r0 | ((int)r1 << 16);
    r0 = f2bf(fmaxf(bf2f((unsigned short)(p.y & 0xffff)) + m[2], 0.f));
    r1 = f2bf(fmaxf(bf2f((unsigned short)((unsigned)p.y >> 16)) + m[3], 0.f));
    o.y = (int)r0 | ((int)r1 << 16);
    r0 = f2bf(fmaxf(bf2f((unsigned short)(p.z & 0xffff)) + m[4], 0.f));
    r1 = f2bf(fmaxf(bf2f((unsigned short)((unsigned)p.z >> 16)) + m[5], 0.f));
    o.z = (int)r0 | ((int)r1 << 16);
    r0 = f2bf(fmaxf(bf2f((unsigned short)(p.w & 0xffff)) + m[6], 0.f));
    r1 = f2bf(fmaxf(bf2f((unsigned short)((unsigned)p.w >> 16)) + m[7], 0.f));
    o.w = (int)r0 | ((int)r1 << 16);
    *(int4*)(X1 + (size_t)node * 256 + c8 * 8) = o;
  }
}

// ---------------- MFMA temporal conv (v3: register prefetch) ----------------
// Same tiling as before (128 rows x 128 cols, NT=2, 4 waves). Staging now
// register-prefetched: next k-chunk's 13 int4 global loads issue before the
// compute barrier; ds_write happens at the top of the next iteration.
template <int TRows, int NT, bool OUT_F32>
__global__ __launch_bounds__(256) void k_conv32(const unsigned short* __restrict__ X,
                                                const unsigned short* __restrict__ Wtb,
                                                const float* __restrict__ bc,
                                                void* __restrict__ Yout) {
  const int CB = NT * 64;                        // block cols
  __shared__ __align__(16) short A_lds[2 * 68 * 40];   // [win][row 0..67][k32 + pad8]
  __shared__ __align__(16) short B_lds[5 * CB * 40];   // [tap*CB + col][k32 + pad8]
  int tid = threadIdx.x;
  int row0 = blockIdx.x * 128;
  int col0 = blockIdx.y * CB;
  int lane = tid & 63, wv = tid >> 6;
  int l31 = lane & 31, khalf = lane >> 5;
  int h = wv & 1, cpart = wv >> 1;

  // --- precompute kb-independent staging descriptors ---
  // A: u = tid + j*256, j=0..2 ; valid if u<544
  bool av[3]; int alds[3]; const unsigned short* aptr[3]; bool ain[3];
#pragma unroll
  for (int j = 0; j < 3; ++j) {
    int u = tid + j * 256;
    av[j] = (u < 544);
    int s = (u >= 272) ? 1 : 0;
    int v = u - s * 272;
    int rr = v >> 2, seg = v & 3;
    int base = row0 + s * 64;
    int lo = base & ~(TRows - 1);
    int gr = base + rr - 2;
    alds[j] = (s * 68 + rr) * 40 + seg * 8;
    ain[j] = av[j] && (gr >= lo) && (gr < lo + TRows);
    aptr[j] = X + (size_t)gr * 256 + seg * 8;
  }
  // B: i = 0..5*NT-1
  int blds[5 * NT]; const unsigned short* bptr[5 * NT];
#pragma unroll
  for (int i = 0; i < 5 * NT; ++i) {
    int u = tid + i * 256;
    int r = u >> 2, seg = u & 3;
    int tap = r / CB, col = r % CB;
    blds[i] = r * 40 + seg * 8;
    bptr[i] = Wtb + (size_t)tap * 65536 + (size_t)(col0 + col) * 256 + seg * 8;
  }

  // prologue: prefetch kb=0
  int4 pa[3], pb[5 * NT];
#pragma unroll
  for (int j = 0; j < 3; ++j)
    pa[j] = ain[j] ? *(const int4*)(aptr[j]) : (int4){0, 0, 0, 0};
#pragma unroll
  for (int i = 0; i < 5 * NT; ++i) pb[i] = *(const int4*)(bptr[i]);

  floatx16 acc[2][NT];
#pragma unroll
  for (int rt = 0; rt < 2; ++rt)
#pragma unroll
    for (int ct = 0; ct < NT; ++ct)
#pragma unroll
      for (int r = 0; r < 16; ++r) acc[rt][ct][r] = 0.f;

  for (int kb = 0; kb < 256; kb += 32) {
    __syncthreads();
#pragma unroll
    for (int j = 0; j < 3; ++j)
      if (av[j]) *(int4*)&A_lds[alds[j]] = pa[j];
#pragma unroll
    for (int i = 0; i < 5 * NT; ++i) *(int4*)&B_lds[blds[i]] = pb[i];
    if (kb + 32 < 256) {
#pragma unroll
      for (int j = 0; j < 3; ++j)
        pa[j] = ain[j] ? *(const int4*)(aptr[j] + kb + 32) : (int4){0, 0, 0, 0};
#pragma unroll
      for (int i = 0; i < 5 * NT; ++i) pb[i] = *(const int4*)(bptr[i] + kb + 32);
    }
    __syncthreads();
#pragma unroll
    for (int tap = 0; tap < 5; ++tap) {
#pragma unroll
      for (int ks = 0; ks < 2; ++ks) {
        int ko = ks * 16 + khalf * 8;
        bhalf8 a[2];
#pragma unroll
        for (int rt = 0; rt < 2; ++rt)
          a[rt] = *(const bhalf8*)&A_lds[(h * 68 + rt * 32 + l31 + tap) * 40 + ko];
#pragma unroll
        for (int ct = 0; ct < NT; ++ct) {
          bhalf8 b = *(const bhalf8*)&B_lds[(tap * CB + cpart * NT * 32 + ct * 32 + l31) * 40 + ko];
#pragma unroll
          for (int rt = 0; rt < 2; ++rt)
            acc[rt][ct] = __builtin_amdgcn_mfma_f32_32x32x16_bf16(a[rt], b, acc[rt][ct], 0, 0, 0);
        }
      }
    }
  }

#pragma unroll
  for (int rt = 0; rt < 2; ++rt) {
#pragma unroll
    for (int ct = 0; ct < NT; ++ct) {
      int c = col0 + cpart * NT * 32 + ct * 32 + l31;
      float bv = bc[c];
#pragma unroll
      for (int r = 0; r < 16; r += 2) {
        int rowg = row0 + h * 64 + rt * 32 + 4 * khalf + 8 * (r >> 2) + (r & 3);
        float y0 = fmaxf(acc[rt][ct][r] + bv, 0.f);
        float y1 = fmaxf(acc[rt][ct][r + 1] + bv, 0.f);
        float p = fmaxf(y0, y1);
        int o = rowg >> 1;
        if (OUT_F32) ((float*)Yout)[(size_t)o * 256 + c] = p;
        else ((unsigned short*)Yout)[(size_t)o * 256 + c] = f2bf(p);
      }
    }
  }
}

extern "C" void kernel_launch(void* const* d_in, const int* in_sizes, int n_in,
                              void* d_out, int out_size, void* d_ws, size_t ws_size,
                              hipStream_t stream) {
  const float* data = (const float*)d_in[0];
  const int* ei0 = (const int*)d_in[2];
  const int* ei1 = (const int*)d_in[3];
  const float* W0  = (const float*)d_in[4];
  const float* b0  = (const float*)d_in[5];
  const float* Wc0 = (const float*)d_in[6];
  const float* bc0 = (const float*)d_in[7];
  const float* W1  = (const float*)d_in[8];
  const float* b1  = (const float*)d_in[9];
  const float* Wc1 = (const float*)d_in[10];
  const float* bc1 = (const float*)d_in[11];
  float* out = (float*)d_out;

  char* base = (char*)d_ws;
  size_t off = 0;
  auto alloc = [&](size_t bytes) { void* p = base + off; off += (bytes + 255) & ~(size_t)255; return p; };
  unsigned short* X0b   = (unsigned short*)alloc((size_t)NODE0 * Ff * 2);
  unsigned short* Bm    = (unsigned short*)alloc((size_t)NODE0 * Hh * 2);
  unsigned short* P     = (unsigned short*)alloc((size_t)NODE0 * Hh * 2);
  unsigned short* X1b   = (unsigned short*)alloc((size_t)NODE0 * Hh * 2);
  unsigned short* Y0b   = (unsigned short*)alloc((size_t)NODE1 * Hh * 2);
  unsigned short* Wbot0 = (unsigned short*)alloc(256 * 128 * 2);
  unsigned short* Wd0   = (unsigned short*)alloc(256 * 128 * 2);
  unsigned short* Wbot1 = (unsigned short*)alloc(256 * 256 * 2);
  unsigned short* Wd1   = (unsigned short*)alloc(256 * 256 * 2);
  unsigned short* Wtb0  = (unsigned short*)alloc(5 * 65536 * 2);
  unsigned short* Wtb1  = (unsigned short*)alloc(5 * 65536 * 2);
  int* cnt0  = (int*)alloc(NODE0 * 4);      // cnt0+cnt1 adjacent: one memset
  int* cnt1  = (int*)alloc(NODE1 * 4);
  int* slot0 = (int*)alloc((size_t)NODE0 * CAP * 4);
  int* slot1 = (int*)alloc((size_t)NODE1 * CAP * 4);

  hipMemsetAsync(cnt0, 0, (NODE0 + NODE1) * sizeof(int), stream);

  k_prepfill<<<6528, 256, 0, stream>>>(data, X0b, W0, Wbot0, Wd0, W1, Wbot1, Wd1,
                                       Wc0, Wtb0, Wc1, Wtb1,
                                       ei0, ei1, cnt0, cnt1, slot0, slot1);

  // ---- layer 0 ----
  k_gemm2<<<dim3(NODE0 / 128, 2), 256, 0, stream>>>(X0b, Wbot0, Wd0, Bm, P, 128, b0);
  k_maxg2<<<NODE0 / 4, 256, 0, stream>>>(Bm, cnt0, slot0, P, X1b);
  k_conv32<128, 2, false><<<dim3(NODE0 / 128, 2), 256, 0, stream>>>(X1b, Wtb0, bc0, Y0b);

  // ---- layer 1 ----
  k_gemm2<<<dim3(NODE1 / 128, 2), 256, 0, stream>>>(Y0b, Wbot1, Wd1, Bm, P, 256, b1);
  k_maxg2<<<NODE1 / 4, 256, 0, stream>>>(Bm, cnt1, slot1, P, X1b);
  k_conv32<64, 2, true><<<dim3(NODE1 / 128, 2), 256, 0, stream>>>(X1b, Wtb1, bc1, out);
}

// Round 3
// 262.716 us; speedup vs baseline: 1.2739x; 1.2739x over previous
//
#include <hip/hip_runtime.h>
#include <hip/hip_bf16.h>
#include <math.h>

#define T0 128
#define BN 256           // B*N = 8*32
#define Ff 128
#define Hh 256
#define NODE0 32768      // BN*T0
#define E0 262144        // NODE0*8
#define T1 64
#define NODE1 16384      // BN*T1
#define E1 131072
#define CAP 48           // per-node in-edge capacity; deg ~ Poisson(8), P(>48) ~ 1e-25

typedef __attribute__((ext_vector_type(8))) short bhalf8;
typedef __attribute__((ext_vector_type(4))) float floatx4;
typedef __attribute__((ext_vector_type(16))) float floatx16;

__device__ __forceinline__ unsigned short f2bf(float x) {
  union { float f; unsigned u; } v; v.f = x;
  unsigned r = v.u + 0x7fff + ((v.u >> 16) & 1);
  return (unsigned short)(r >> 16);
}
__device__ __forceinline__ float bf2f(unsigned short b) {
  union { unsigned u; float f; } v; v.u = ((unsigned)b) << 16;
  return v.f;
}
// update two running maxes from one packed int (2 bf16)
__device__ __forceinline__ void max2(float& mlo, float& mhi, int p) {
  union { unsigned u; float f; } lo, hi;
  lo.u = ((unsigned)p) << 16;
  hi.u = ((unsigned)p) & 0xffff0000u;
  mlo = fmaxf(mlo, lo.f);
  mhi = fmaxf(mhi, hi.f);
}

// ---------------- fused prep + edge-fill kernel ----------------
__global__ void k_prepfill(const float* __restrict__ data, unsigned short* __restrict__ X0b,
                           const float* __restrict__ W0, unsigned short* __restrict__ Wbot0,
                           unsigned short* __restrict__ Wd0,
                           const float* __restrict__ W1, unsigned short* __restrict__ Wbot1,
                           unsigned short* __restrict__ Wd1,
                           const float* __restrict__ Wc0, unsigned short* __restrict__ Wtb0,
                           const float* __restrict__ Wc1, unsigned short* __restrict__ Wtb1,
                           const int* __restrict__ ei0, const int* __restrict__ ei1,
                           int* __restrict__ cnt0, int* __restrict__ cnt1,
                           int* __restrict__ slot0, int* __restrict__ slot1) {
  int b = blockIdx.x;
  int tid = threadIdx.x;
  if (b < 2048) {
    int idx = b * 256 + tid;          // NODE0*16, 8 elems each
    int c8 = idx & 15;
    int r  = idx >> 4;
    int t  = r & (T0 - 1);
    int bn = r >> 7;
    const float* s = data + ((size_t)t * BN + bn) * Ff + c8 * 8;
    float4 a = *(const float4*)s;
    float4 bb = *(const float4*)(s + 4);
    unsigned short o[8];
    o[0] = f2bf(a.x); o[1] = f2bf(a.y); o[2] = f2bf(a.z); o[3] = f2bf(a.w);
    o[4] = f2bf(bb.x); o[5] = f2bf(bb.y); o[6] = f2bf(bb.z); o[7] = f2bf(bb.w);
    *(int4*)(X0b + ((size_t)(bn * T0 + t) * Ff + c8 * 8)) = *(int4*)o;
  } else if (b < 2176) {
    int idx = (b - 2048) * 256 + tid; // 32768 = 256*128
    int n = idx >> 7, k = idx & 127;
    float top = W0[(size_t)k * 256 + n];
    float bot = W0[(size_t)(128 + k) * 256 + n];
    Wbot0[idx] = f2bf(bot);
    Wd0[idx]   = f2bf(top - bot);
  } else if (b < 2432) {
    int idx = (b - 2176) * 256 + tid; // 65536 = 256*256
    int n = idx >> 8, k = idx & 255;
    float top = W1[(size_t)k * 256 + n];
    float bot = W1[(size_t)(256 + k) * 256 + n];
    Wbot1[idx] = f2bf(bot);
    Wd1[idx]   = f2bf(top - bot);
  } else if (b < 3712) {
    int idx = (b - 2432) * 256 + tid; // 5*65536
    int tap = idx >> 16, o = (idx >> 8) & 255, i = idx & 255;
    Wtb0[idx] = f2bf(Wc0[((size_t)o * 256 + i) * 5 + tap]);
  } else if (b < 4992) {
    int idx = (b - 3712) * 256 + tid;
    int tap = idx >> 16, o = (idx >> 8) & 255, i = idx & 255;
    Wtb1[idx] = f2bf(Wc1[((size_t)o * 256 + i) * 5 + tap]);
  } else {
    int e = (b - 4992) * 256 + tid;   // E0+E1 = 393216 over 1536 blocks
    if (e < E0) {
      int d = ei0[E0 + e];
      int p = atomicAdd(&cnt0[d], 1);
      if (p < CAP) slot0[(size_t)d * CAP + p] = ei0[e];
    } else {
      int e2 = e - E0;
      int d = ei1[E1 + e2];
      int p = atomicAdd(&cnt1[d], 1);
      if (p < CAP) slot1[(size_t)d * CAP + p] = ei1[e2];
    }
  }
}

// ---------------- fused dual-output MFMA GEMM (v3, kept) ----------------
// 128x128 block, 4 waves, 2 row-tiles/wave.
//  - register prefetch: next k-tile's global loads issued before the compute
//    barrier, ds_written at the top of the next iteration (48 VGPRs held;
//    128 acc + 48 + addr ~ 200 VGPR, fits without spill).
//  - swapped-operand MFMA (mfma(b,a)): lane holds ONE node row with 4
//    consecutive channels per acc reg -> epilogue is 32 ushort4 stores
//    instead of 128 scalar 2B stores.
__global__ __launch_bounds__(256) void k_gemm2(const unsigned short* __restrict__ A,
                                               const unsigned short* __restrict__ Wbot,
                                               const unsigned short* __restrict__ Wd,
                                               unsigned short* __restrict__ Bm,
                                               unsigned short* __restrict__ P, int K,
                                               const float* __restrict__ bias) {
  __shared__ __align__(16) short A_lds[128 * 72];
  __shared__ __align__(16) short B0_lds[128 * 72];
  __shared__ __align__(16) short B1_lds[128 * 72];
  int tid = threadIdx.x;
  int row0 = blockIdx.x * 128;
  int col0 = blockIdx.y * 128;
  int lane = tid & 63, wv = tid >> 6;
  int m16 = lane & 15, quad = lane >> 4;
  int sr = tid >> 3, sseg = tid & 7;

  const unsigned short* Abase  = A    + (size_t)(row0 + sr) * K + sseg * 8;
  const unsigned short* B0base = Wbot + (size_t)(col0 + sr) * K + sseg * 8;
  const unsigned short* B1base = Wd   + (size_t)(col0 + sr) * K + sseg * 8;

  int4 ra[4], rb0[4], rb1[4];
#pragma unroll
  for (int i = 0; i < 4; ++i) {
    ra[i]  = *(const int4*)(Abase  + (size_t)i * 32 * K);
    rb0[i] = *(const int4*)(B0base + (size_t)i * 32 * K);
    rb1[i] = *(const int4*)(B1base + (size_t)i * 32 * K);
  }

  floatx4 accB[2][8], accP[2][8];
#pragma unroll
  for (int rt = 0; rt < 2; ++rt)
#pragma unroll
    for (int nt = 0; nt < 8; ++nt) {
      accB[rt][nt] = (floatx4){0.f, 0.f, 0.f, 0.f};
      accP[rt][nt] = (floatx4){0.f, 0.f, 0.f, 0.f};
    }

  for (int kb = 0; kb < K; kb += 64) {
    __syncthreads();
#pragma unroll
    for (int i = 0; i < 4; ++i) {
      int r = sr + i * 32;
      *(int4*)&A_lds[r * 72 + sseg * 8]  = ra[i];
      *(int4*)&B0_lds[r * 72 + sseg * 8] = rb0[i];
      *(int4*)&B1_lds[r * 72 + sseg * 8] = rb1[i];
    }
    if (kb + 64 < K) {
#pragma unroll
      for (int i = 0; i < 4; ++i) {
        ra[i]  = *(const int4*)(Abase  + (size_t)i * 32 * K + kb + 64);
        rb0[i] = *(const int4*)(B0base + (size_t)i * 32 * K + kb + 64);
        rb1[i] = *(const int4*)(B1base + (size_t)i * 32 * K + kb + 64);
      }
    }
    __syncthreads();
#pragma unroll
    for (int ks = 0; ks < 2; ++ks) {
      bhalf8 a0 = *(const bhalf8*)&A_lds[(wv * 32 + m16) * 72 + ks * 32 + quad * 8];
      bhalf8 a1 = *(const bhalf8*)&A_lds[(wv * 32 + 16 + m16) * 72 + ks * 32 + quad * 8];
#pragma unroll
      for (int nt = 0; nt < 8; ++nt) {
        bhalf8 b0 = *(const bhalf8*)&B0_lds[(nt * 16 + m16) * 72 + ks * 32 + quad * 8];
        accB[0][nt] = __builtin_amdgcn_mfma_f32_16x16x32_bf16(b0, a0, accB[0][nt], 0, 0, 0);
        accB[1][nt] = __builtin_amdgcn_mfma_f32_16x16x32_bf16(b0, a1, accB[1][nt], 0, 0, 0);
        bhalf8 b1 = *(const bhalf8*)&B1_lds[(nt * 16 + m16) * 72 + ks * 32 + quad * 8];
        accP[0][nt] = __builtin_amdgcn_mfma_f32_16x16x32_bf16(b1, a0, accP[0][nt], 0, 0, 0);
        accP[1][nt] = __builtin_amdgcn_mfma_f32_16x16x32_bf16(b1, a1, accP[1][nt], 0, 0, 0);
      }
    }
  }

  // swapped C/D layout: value = C[node=row0+wv*32+rt*16+m16][col0+nt*16+quad*4+r]
#pragma unroll
  for (int rt = 0; rt < 2; ++rt) {
    int row = row0 + wv * 32 + rt * 16 + m16;
#pragma unroll
    for (int nt = 0; nt < 8; ++nt) {
      int c = col0 + nt * 16 + quad * 4;
      float4 bv = *(const float4*)&bias[c];
      ushort4 ob, op;
      ob.x = f2bf(accB[rt][nt][0]); ob.y = f2bf(accB[rt][nt][1]);
      ob.z = f2bf(accB[rt][nt][2]); ob.w = f2bf(accB[rt][nt][3]);
      op.x = f2bf(accP[rt][nt][0] + bv.x); op.y = f2bf(accP[rt][nt][1] + bv.y);
      op.z = f2bf(accP[rt][nt][2] + bv.z); op.w = f2bf(accP[rt][nt][3] + bv.w);
      *(ushort4*)(Bm + (size_t)row * 256 + c) = ob;
      *(ushort4*)(P  + (size_t)row * 256 + c) = op;
    }
  }
}

// ---------------- segment max + fused relu epilogue (v2, kept) ----------------
__global__ __launch_bounds__(256) void k_maxg2(const unsigned short* __restrict__ Bm,
                                               const int* __restrict__ cnt,
                                               const int* __restrict__ slot,
                                               const unsigned short* __restrict__ P,
                                               unsigned short* __restrict__ X1) {
  int node = blockIdx.x * 4 + (threadIdx.x >> 6);
  int lane = threadIdx.x & 63;
  int half = lane >> 5, c8 = lane & 31;
  int n = cnt[node];
  if (n > CAP) n = CAP;
  const int* sl = slot + (size_t)node * CAP;
  float m[8];
#pragma unroll
  for (int e = 0; e < 8; ++e) m[e] = -INFINITY;
  for (int i = 0; i < n; i += 8) {
    int s[4];
#pragma unroll
    for (int j = 0; j < 4; ++j) {
      int idx = i + 2 * j + half;
      s[j] = sl[(idx < n) ? idx : (n - 1)];
    }
    int4 v[4];
#pragma unroll
    for (int j = 0; j < 4; ++j)
      v[j] = *(const int4*)(Bm + (size_t)s[j] * 256 + c8 * 8);
#pragma unroll
    for (int j = 0; j < 4; ++j) {
      max2(m[0], m[1], v[j].x);
      max2(m[2], m[3], v[j].y);
      max2(m[4], m[5], v[j].z);
      max2(m[6], m[7], v[j].w);
    }
  }
#pragma unroll
  for (int e = 0; e < 8; ++e) m[e] = fmaxf(m[e], __shfl_xor(m[e], 32));
  if (half == 0) {
    int4 p = *(const int4*)(P + (size_t)node * 256 + c8 * 8);
    int4 o;
    unsigned short r0, r1;
    r0 = f2bf(fmaxf(bf2f((unsigned short)(p.x & 0xffff)) + m[0], 0.f));
    r1 = f2bf(fmaxf(bf2f((unsigned short)((unsigned)p.x >> 16)) + m[1], 0.f));
    o.x = (int)r0 | ((int)r1 << 16);
    r0 = f2bf(fmaxf(bf2f((unsigned short)(p.y & 0xffff)) + m[2], 0.f));
    r1 = f2bf(fmaxf(bf2f((unsigned short)((unsigned)p.y >> 16)) + m[3], 0.f));
    o.y = (int)r0 | ((int)r1 << 16);
    r0 = f2bf(fmaxf(bf2f((unsigned short)(p.z & 0xffff)) + m[4], 0.f));
    r1 = f2bf(fmaxf(bf2f((unsigned short)((unsigned)p.z >> 16)) + m[5], 0.f));
    o.z = (int)r0 | ((int)r1 << 16);
    r0 = f2bf(fmaxf(bf2f((unsigned short)(p.w & 0xffff)) + m[6], 0.f));
    r1 = f2bf(fmaxf(bf2f((unsigned short)((unsigned)p.w >> 16)) + m[7], 0.f));
    o.w = (int)r0 | ((int)r1 << 16);
    *(int4*)(X1 + (size_t)node * 256 + c8 * 8) = o;
  }
}

// ---------------- MFMA temporal conv (round-1 direct staging, REVERTED) ----------------
// The register-prefetch variant spilled (VGPR 96 + 129MB scratch writes,
// 65us/dispatch). Direct staging keeps live regs = 64 acc + few addr.
template <int TRows, int NT, bool OUT_F32>
__global__ __launch_bounds__(256) void k_conv32(const unsigned short* __restrict__ X,
                                                const unsigned short* __restrict__ Wtb,
                                                const float* __restrict__ bc,
                                                void* __restrict__ Yout) {
  const int CB = NT * 64;                        // block cols
  __shared__ __align__(16) short A_lds[2 * 68 * 40];   // [win][row 0..67][k32 + pad8]
  __shared__ __align__(16) short B_lds[5 * CB * 40];   // [tap*CB + col][k32 + pad8]
  int tid = threadIdx.x;
  int row0 = blockIdx.x * 128;
  int col0 = blockIdx.y * CB;
  int lane = tid & 63, wv = tid >> 6;
  int l31 = lane & 31, khalf = lane >> 5;
  int h = wv & 1, cpart = wv >> 1;

  floatx16 acc[2][NT];
#pragma unroll
  for (int rt = 0; rt < 2; ++rt)
#pragma unroll
    for (int ct = 0; ct < NT; ++ct)
#pragma unroll
      for (int r = 0; r < 16; ++r) acc[rt][ct][r] = 0.f;

  for (int kb = 0; kb < 256; kb += 32) {
    __syncthreads();
    // stage A: two 68-row halo windows (rows base-2 .. base+66), zero outside bn
    for (int u = tid; u < 544; u += 256) {
      int s = (u >= 272) ? 1 : 0;
      int v = u - s * 272;
      int rr = v >> 2, seg = v & 3;
      int base = row0 + s * 64;
      int lo = base & ~(TRows - 1);
      int gr = base + rr - 2;
      int4 val = {0, 0, 0, 0};
      if (gr >= lo && gr < lo + TRows)
        val = *(const int4*)(X + (size_t)gr * 256 + kb + seg * 8);
      *(int4*)&A_lds[(s * 68 + rr) * 40 + seg * 8] = val;
    }
    // stage B: 5 taps x CB cols x 32 k
#pragma unroll
    for (int i = 0; i < 5 * NT; ++i) {
      int u = tid + i * 256;            // 5*CB rows x 4 segs
      int r = u >> 2, seg = u & 3;      // r = tap*CB + col
      int tap = r / CB, col = r % CB;
      *(int4*)&B_lds[r * 40 + seg * 8] =
          *(const int4*)(Wtb + (size_t)tap * 65536 + (size_t)(col0 + col) * 256 + kb + seg * 8);
    }
    __syncthreads();
#pragma unroll
    for (int tap = 0; tap < 5; ++tap) {
#pragma unroll
      for (int ks = 0; ks < 2; ++ks) {
        int ko = ks * 16 + khalf * 8;
        bhalf8 a[2];
#pragma unroll
        for (int rt = 0; rt < 2; ++rt)
          a[rt] = *(const bhalf8*)&A_lds[(h * 68 + rt * 32 + l31 + tap) * 40 + ko];
#pragma unroll
        for (int ct = 0; ct < NT; ++ct) {
          bhalf8 b = *(const bhalf8*)&B_lds[(tap * CB + cpart * NT * 32 + ct * 32 + l31) * 40 + ko];
#pragma unroll
          for (int rt = 0; rt < 2; ++rt)
            acc[rt][ct] = __builtin_amdgcn_mfma_f32_32x32x16_bf16(a[rt], b, acc[rt][ct], 0, 0, 0);
        }
      }
    }
  }

#pragma unroll
  for (int rt = 0; rt < 2; ++rt) {
#pragma unroll
    for (int ct = 0; ct < NT; ++ct) {
      int c = col0 + cpart * NT * 32 + ct * 32 + l31;
      float bv = bc[c];
#pragma unroll
      for (int r = 0; r < 16; r += 2) {
        int rowg = row0 + h * 64 + rt * 32 + 4 * khalf + 8 * (r >> 2) + (r & 3);
        float y0 = fmaxf(acc[rt][ct][r] + bv, 0.f);
        float y1 = fmaxf(acc[rt][ct][r + 1] + bv, 0.f);
        float p = fmaxf(y0, y1);
        int o = rowg >> 1;
        if (OUT_F32) ((float*)Yout)[(size_t)o * 256 + c] = p;
        else ((unsigned short*)Yout)[(size_t)o * 256 + c] = f2bf(p);
      }
    }
  }
}

extern "C" void kernel_launch(void* const* d_in, const int* in_sizes, int n_in,
                              void* d_out, int out_size, void* d_ws, size_t ws_size,
                              hipStream_t stream) {
  const float* data = (const float*)d_in[0];
  const int* ei0 = (const int*)d_in[2];
  const int* ei1 = (const int*)d_in[3];
  const float* W0  = (const float*)d_in[4];
  const float* b0  = (const float*)d_in[5];
  const float* Wc0 = (const float*)d_in[6];
  const float* bc0 = (const float*)d_in[7];
  const float* W1  = (const float*)d_in[8];
  const float* b1  = (const float*)d_in[9];
  const float* Wc1 = (const float*)d_in[10];
  const float* bc1 = (const float*)d_in[11];
  float* out = (float*)d_out;

  char* base = (char*)d_ws;
  size_t off = 0;
  auto alloc = [&](size_t bytes) { void* p = base + off; off += (bytes + 255) & ~(size_t)255; return p; };
  unsigned short* X0b   = (unsigned short*)alloc((size_t)NODE0 * Ff * 2);
  unsigned short* Bm    = (unsigned short*)alloc((size_t)NODE0 * Hh * 2);
  unsigned short* P     = (unsigned short*)alloc((size_t)NODE0 * Hh * 2);
  unsigned short* X1b   = (unsigned short*)alloc((size_t)NODE0 * Hh * 2);
  unsigned short* Y0b   = (unsigned short*)alloc((size_t)NODE1 * Hh * 2);
  unsigned short* Wbot0 = (unsigned short*)alloc(256 * 128 * 2);
  unsigned short* Wd0   = (unsigned short*)alloc(256 * 128 * 2);
  unsigned short* Wbot1 = (unsigned short*)alloc(256 * 256 * 2);
  unsigned short* Wd1   = (unsigned short*)alloc(256 * 256 * 2);
  unsigned short* Wtb0  = (unsigned short*)alloc(5 * 65536 * 2);
  unsigned short* Wtb1  = (unsigned short*)alloc(5 * 65536 * 2);
  int* cnt0  = (int*)alloc(NODE0 * 4);      // cnt0+cnt1 adjacent: one memset
  int* cnt1  = (int*)alloc(NODE1 * 4);
  int* slot0 = (int*)alloc((size_t)NODE0 * CAP * 4);
  int* slot1 = (int*)alloc((size_t)NODE1 * CAP * 4);

  hipMemsetAsync(cnt0, 0, (NODE0 + NODE1) * sizeof(int), stream);

  k_prepfill<<<6528, 256, 0, stream>>>(data, X0b, W0, Wbot0, Wd0, W1, Wbot1, Wd1,
                                       Wc0, Wtb0, Wc1, Wtb1,
                                       ei0, ei1, cnt0, cnt1, slot0, slot1);

  // ---- layer 0 ----
  k_gemm2<<<dim3(NODE0 / 128, 2), 256, 0, stream>>>(X0b, Wbot0, Wd0, Bm, P, 128, b0);
  k_maxg2<<<NODE0 / 4, 256, 0, stream>>>(Bm, cnt0, slot0, P, X1b);
  k_conv32<128, 2, false><<<dim3(NODE0 / 128, 2), 256, 0, stream>>>(X1b, Wtb0, bc0, Y0b);

  // ---- layer 1 ----
  k_gemm2<<<dim3(NODE1 / 128, 2), 256, 0, stream>>>(Y0b, Wbot1, Wd1, Bm, P, 256, b1);
  k_maxg2<<<NODE1 / 4, 256, 0, stream>>>(Bm, cnt1, slot1, P, X1b);
  k_conv32<64, 2, true><<<dim3(NODE1 / 128, 2), 256, 0, stream>>>(X1b, Wtb1, bc1, out);
}

// Round 4
// 219.176 us; speedup vs baseline: 1.5270x; 1.1987x over previous
//
#include <hip/hip_runtime.h>
#include <hip/hip_bf16.h>
#include <math.h>

#define T0 128
#define BN 256           // B*N = 8*32
#define Ff 128
#define Hh 256
#define NODE0 32768      // BN*T0
#define E0 262144        // NODE0*8
#define T1 64
#define NODE1 16384      // BN*T1
#define E1 131072
#define CAP 48           // per-node in-edge capacity; deg ~ Poisson(8), P(>48) ~ 1e-25

typedef __attribute__((ext_vector_type(8))) short bhalf8;
typedef __attribute__((ext_vector_type(4))) float floatx4;
typedef __attribute__((ext_vector_type(16))) float floatx16;

__device__ __forceinline__ unsigned short f2bf(float x) {
  union { float f; unsigned u; } v; v.f = x;
  unsigned r = v.u + 0x7fff + ((v.u >> 16) & 1);
  return (unsigned short)(r >> 16);
}
__device__ __forceinline__ float bf2f(unsigned short b) {
  union { unsigned u; float f; } v; v.u = ((unsigned)b) << 16;
  return v.f;
}
// update two running maxes from one packed int (2 bf16)
__device__ __forceinline__ void max2(float& mlo, float& mhi, int p) {
  union { unsigned u; float f; } lo, hi;
  lo.u = ((unsigned)p) << 16;
  hi.u = ((unsigned)p) & 0xffff0000u;
  mlo = fmaxf(mlo, lo.f);
  mhi = fmaxf(mhi, hi.f);
}

// ---------------- fused prep + edge-fill kernel ----------------
__global__ void k_prepfill(const float* __restrict__ data, unsigned short* __restrict__ X0b,
                           const float* __restrict__ W0, unsigned short* __restrict__ Wbot0,
                           unsigned short* __restrict__ Wd0,
                           const float* __restrict__ W1, unsigned short* __restrict__ Wbot1,
                           unsigned short* __restrict__ Wd1,
                           const float* __restrict__ Wc0, unsigned short* __restrict__ Wtb0,
                           const float* __restrict__ Wc1, unsigned short* __restrict__ Wtb1,
                           const int* __restrict__ ei0, const int* __restrict__ ei1,
                           int* __restrict__ cnt0, int* __restrict__ cnt1,
                           int* __restrict__ slot0, int* __restrict__ slot1) {
  int b = blockIdx.x;
  int tid = threadIdx.x;
  if (b < 2048) {
    int idx = b * 256 + tid;          // NODE0*16, 8 elems each
    int c8 = idx & 15;
    int r  = idx >> 4;
    int t  = r & (T0 - 1);
    int bn = r >> 7;
    const float* s = data + ((size_t)t * BN + bn) * Ff + c8 * 8;
    float4 a = *(const float4*)s;
    float4 bb = *(const float4*)(s + 4);
    unsigned short o[8];
    o[0] = f2bf(a.x); o[1] = f2bf(a.y); o[2] = f2bf(a.z); o[3] = f2bf(a.w);
    o[4] = f2bf(bb.x); o[5] = f2bf(bb.y); o[6] = f2bf(bb.z); o[7] = f2bf(bb.w);
    *(int4*)(X0b + ((size_t)(bn * T0 + t) * Ff + c8 * 8)) = *(int4*)o;
  } else if (b < 2176) {
    int idx = (b - 2048) * 256 + tid; // 32768 = 256*128
    int n = idx >> 7, k = idx & 127;
    float top = W0[(size_t)k * 256 + n];
    float bot = W0[(size_t)(128 + k) * 256 + n];
    Wbot0[idx] = f2bf(bot);
    Wd0[idx]   = f2bf(top - bot);
  } else if (b < 2432) {
    int idx = (b - 2176) * 256 + tid; // 65536 = 256*256
    int n = idx >> 8, k = idx & 255;
    float top = W1[(size_t)k * 256 + n];
    float bot = W1[(size_t)(256 + k) * 256 + n];
    Wbot1[idx] = f2bf(bot);
    Wd1[idx]   = f2bf(top - bot);
  } else if (b < 3712) {
    int idx = (b - 2432) * 256 + tid; // 5*65536
    int tap = idx >> 16, o = (idx >> 8) & 255, i = idx & 255;
    Wtb0[idx] = f2bf(Wc0[((size_t)o * 256 + i) * 5 + tap]);
  } else if (b < 4992) {
    int idx = (b - 3712) * 256 + tid;
    int tap = idx >> 16, o = (idx >> 8) & 255, i = idx & 255;
    Wtb1[idx] = f2bf(Wc1[((size_t)o * 256 + i) * 5 + tap]);
  } else {
    int e = (b - 4992) * 256 + tid;   // E0+E1 = 393216 over 1536 blocks
    if (e < E0) {
      int d = ei0[E0 + e];
      int p = atomicAdd(&cnt0[d], 1);
      if (p < CAP) slot0[(size_t)d * CAP + p] = ei0[e];
    } else {
      int e2 = e - E0;
      int d = ei1[E1 + e2];
      int p = atomicAdd(&cnt1[d], 1);
      if (p < CAP) slot1[(size_t)d * CAP + p] = ei1[e2];
    }
  }
}

// ---------------- fused dual-output MFMA GEMM (v4: coalesced epilogue) ----------------
// 128x128 block, 4 waves, 2 row-tiles/wave, swapped-operand MFMA (verified r3).
// NEW: epilogue stages packed bf16 results in LDS (aliased over the dead A/B0
// staging region), then the block streams them out as 256B-contiguous,
// 128B-aligned row segments. The old direct epilogue scattered 32B segments
// across 16 rows per wave -> partial-line RMW (WRITE_SIZE 49MB vs 33.6MB
// ideal, write BW capped ~1.4TB/s, 43.5us/dispatch).
__global__ __launch_bounds__(256) void k_gemm2(const unsigned short* __restrict__ A,
                                               const unsigned short* __restrict__ Wbot,
                                               const unsigned short* __restrict__ Wd,
                                               unsigned short* __restrict__ Bm,
                                               unsigned short* __restrict__ P, int K,
                                               const float* __restrict__ bias) {
  __shared__ __align__(16) short S_lds[3 * 128 * 72];  // 55.3 KB
  short* A_lds  = S_lds;
  short* B0_lds = S_lds + 128 * 72;
  short* B1_lds = S_lds + 2 * 128 * 72;
  short* E_lds  = S_lds;            // epilogue tile: 128 rows x 136 shorts (17408 <= 18432)
  int tid = threadIdx.x;
  int row0 = blockIdx.x * 128;
  int col0 = blockIdx.y * 128;
  int lane = tid & 63, wv = tid >> 6;
  int m16 = lane & 15, quad = lane >> 4;
  int sr = tid >> 3, sseg = tid & 7;

  floatx4 accB[2][8], accP[2][8];
#pragma unroll
  for (int rt = 0; rt < 2; ++rt)
#pragma unroll
    for (int nt = 0; nt < 8; ++nt) {
      accB[rt][nt] = (floatx4){0.f, 0.f, 0.f, 0.f};
      accP[rt][nt] = (floatx4){0.f, 0.f, 0.f, 0.f};
    }

  for (int kb = 0; kb < K; kb += 64) {
    __syncthreads();
#pragma unroll
    for (int i = 0; i < 4; ++i) {
      int r = sr + i * 32;
      *(int4*)&A_lds[r * 72 + sseg * 8] =
          *(const int4*)(A + (size_t)(row0 + r) * K + kb + sseg * 8);
      *(int4*)&B0_lds[r * 72 + sseg * 8] =
          *(const int4*)(Wbot + (size_t)(col0 + r) * K + kb + sseg * 8);
      *(int4*)&B1_lds[r * 72 + sseg * 8] =
          *(const int4*)(Wd + (size_t)(col0 + r) * K + kb + sseg * 8);
    }
    __syncthreads();
#pragma unroll
    for (int ks = 0; ks < 2; ++ks) {
      bhalf8 a0 = *(const bhalf8*)&A_lds[(wv * 32 + m16) * 72 + ks * 32 + quad * 8];
      bhalf8 a1 = *(const bhalf8*)&A_lds[(wv * 32 + 16 + m16) * 72 + ks * 32 + quad * 8];
#pragma unroll
      for (int nt = 0; nt < 8; ++nt) {
        bhalf8 b0 = *(const bhalf8*)&B0_lds[(nt * 16 + m16) * 72 + ks * 32 + quad * 8];
        accB[0][nt] = __builtin_amdgcn_mfma_f32_16x16x32_bf16(b0, a0, accB[0][nt], 0, 0, 0);
        accB[1][nt] = __builtin_amdgcn_mfma_f32_16x16x32_bf16(b0, a1, accB[1][nt], 0, 0, 0);
        bhalf8 b1 = *(const bhalf8*)&B1_lds[(nt * 16 + m16) * 72 + ks * 32 + quad * 8];
        accP[0][nt] = __builtin_amdgcn_mfma_f32_16x16x32_bf16(b1, a0, accP[0][nt], 0, 0, 0);
        accP[1][nt] = __builtin_amdgcn_mfma_f32_16x16x32_bf16(b1, a1, accP[1][nt], 0, 0, 0);
      }
    }
  }

  // swapped C/D layout: lane holds node row = row0+wv*32+rt*16+m16,
  // channels col0 + nt*16 + quad*4 + r.
  const int ESTR = 136;  // shorts per staged row (272B; keeps 16B alignment)
  __syncthreads();       // all waves done reading staging LDS before overwrite

  // ---- Bm ----
#pragma unroll
  for (int rt = 0; rt < 2; ++rt) {
    int lr = wv * 32 + rt * 16 + m16;
#pragma unroll
    for (int nt = 0; nt < 8; ++nt) {
      ushort4 ob;
      ob.x = f2bf(accB[rt][nt][0]); ob.y = f2bf(accB[rt][nt][1]);
      ob.z = f2bf(accB[rt][nt][2]); ob.w = f2bf(accB[rt][nt][3]);
      *(ushort4*)&E_lds[lr * ESTR + nt * 16 + quad * 4] = ob;
    }
  }
  __syncthreads();
#pragma unroll
  for (int i = 0; i < 8; ++i) {
    int u = tid + i * 256;           // 2048 chunks = 128 rows x 16
    int r = u >> 4, ch = u & 15;
    int4 v = *(const int4*)&E_lds[r * ESTR + ch * 8];
    *(int4*)(Bm + (size_t)(row0 + r) * 256 + col0 + ch * 8) = v;
  }
  __syncthreads();

  // ---- P (+bias) ----
#pragma unroll
  for (int rt = 0; rt < 2; ++rt) {
    int lr = wv * 32 + rt * 16 + m16;
#pragma unroll
    for (int nt = 0; nt < 8; ++nt) {
      int c = col0 + nt * 16 + quad * 4;
      float4 bv = *(const float4*)&bias[c];
      ushort4 op;
      op.x = f2bf(accP[rt][nt][0] + bv.x); op.y = f2bf(accP[rt][nt][1] + bv.y);
      op.z = f2bf(accP[rt][nt][2] + bv.z); op.w = f2bf(accP[rt][nt][3] + bv.w);
      *(ushort4*)&E_lds[lr * ESTR + nt * 16 + quad * 4] = op;
    }
  }
  __syncthreads();
#pragma unroll
  for (int i = 0; i < 8; ++i) {
    int u = tid + i * 256;
    int r = u >> 4, ch = u & 15;
    int4 v = *(const int4*)&E_lds[r * ESTR + ch * 8];
    *(int4*)(P + (size_t)(row0 + r) * 256 + col0 + ch * 8) = v;
  }
}

// ---------------- segment max + fused relu epilogue (v2, kept) ----------------
__global__ __launch_bounds__(256) void k_maxg2(const unsigned short* __restrict__ Bm,
                                               const int* __restrict__ cnt,
                                               const int* __restrict__ slot,
                                               const unsigned short* __restrict__ P,
                                               unsigned short* __restrict__ X1) {
  int node = blockIdx.x * 4 + (threadIdx.x >> 6);
  int lane = threadIdx.x & 63;
  int half = lane >> 5, c8 = lane & 31;
  int n = cnt[node];
  if (n > CAP) n = CAP;
  const int* sl = slot + (size_t)node * CAP;
  float m[8];
#pragma unroll
  for (int e = 0; e < 8; ++e) m[e] = -INFINITY;
  for (int i = 0; i < n; i += 8) {
    int s[4];
#pragma unroll
    for (int j = 0; j < 4; ++j) {
      int idx = i + 2 * j + half;
      s[j] = sl[(idx < n) ? idx : (n - 1)];
    }
    int4 v[4];
#pragma unroll
    for (int j = 0; j < 4; ++j)
      v[j] = *(const int4*)(Bm + (size_t)s[j] * 256 + c8 * 8);
#pragma unroll
    for (int j = 0; j < 4; ++j) {
      max2(m[0], m[1], v[j].x);
      max2(m[2], m[3], v[j].y);
      max2(m[4], m[5], v[j].z);
      max2(m[6], m[7], v[j].w);
    }
  }
#pragma unroll
  for (int e = 0; e < 8; ++e) m[e] = fmaxf(m[e], __shfl_xor(m[e], 32));
  if (half == 0) {
    int4 p = *(const int4*)(P + (size_t)node * 256 + c8 * 8);
    int4 o;
    unsigned short r0, r1;
    r0 = f2bf(fmaxf(bf2f((unsigned short)(p.x & 0xffff)) + m[0], 0.f));
    r1 = f2bf(fmaxf(bf2f((unsigned short)((unsigned)p.x >> 16)) + m[1], 0.f));
    o.x = (int)r0 | ((int)r1 << 16);
    r0 = f2bf(fmaxf(bf2f((unsigned short)(p.y & 0xffff)) + m[2], 0.f));
    r1 = f2bf(fmaxf(bf2f((unsigned short)((unsigned)p.y >> 16)) + m[3], 0.f));
    o.y = (int)r0 | ((int)r1 << 16);
    r0 = f2bf(fmaxf(bf2f((unsigned short)(p.z & 0xffff)) + m[4], 0.f));
    r1 = f2bf(fmaxf(bf2f((unsigned short)((unsigned)p.z >> 16)) + m[5], 0.f));
    o.z = (int)r0 | ((int)r1 << 16);
    r0 = f2bf(fmaxf(bf2f((unsigned short)(p.w & 0xffff)) + m[6], 0.f));
    r1 = f2bf(fmaxf(bf2f((unsigned short)((unsigned)p.w >> 16)) + m[7], 0.f));
    o.w = (int)r0 | ((int)r1 << 16);
    *(int4*)(X1 + (size_t)node * 256 + c8 * 8) = o;
  }
}

// ---------------- MFMA temporal conv (direct staging, NT=2) ----------------
template <int TRows, int NT, bool OUT_F32>
__global__ __launch_bounds__(256) void k_conv32(const unsigned short* __restrict__ X,
                                                const unsigned short* __restrict__ Wtb,
                                                const float* __restrict__ bc,
                                                void* __restrict__ Yout) {
  const int CB = NT * 64;                        // block cols
  __shared__ __align__(16) short A_lds[2 * 68 * 40];   // [win][row 0..67][k32 + pad8]
  __shared__ __align__(16) short B_lds[5 * CB * 40];   // [tap*CB + col][k32 + pad8]
  int tid = threadIdx.x;
  int row0 = blockIdx.x * 128;
  int col0 = blockIdx.y * CB;
  int lane = tid & 63, wv = tid >> 6;
  int l31 = lane & 31, khalf = lane >> 5;
  int h = wv & 1, cpart = wv >> 1;

  floatx16 acc[2][NT];
#pragma unroll
  for (int rt = 0; rt < 2; ++rt)
#pragma unroll
    for (int ct = 0; ct < NT; ++ct)
#pragma unroll
      for (int r = 0; r < 16; ++r) acc[rt][ct][r] = 0.f;

  for (int kb = 0; kb < 256; kb += 32) {
    __syncthreads();
    // stage A: two 68-row halo windows (rows base-2 .. base+66), zero outside bn
    for (int u = tid; u < 544; u += 256) {
      int s = (u >= 272) ? 1 : 0;
      int v = u - s * 272;
      int rr = v >> 2, seg = v & 3;
      int base = row0 + s * 64;
      int lo = base & ~(TRows - 1);
      int gr = base + rr - 2;
      int4 val = {0, 0, 0, 0};
      if (gr >= lo && gr < lo + TRows)
        val = *(const int4*)(X + (size_t)gr * 256 + kb + seg * 8);
      *(int4*)&A_lds[(s * 68 + rr) * 40 + seg * 8] = val;
    }
    // stage B: 5 taps x CB cols x 32 k
#pragma unroll
    for (int i = 0; i < 5 * NT; ++i) {
      int u = tid + i * 256;            // 5*CB rows x 4 segs
      int r = u >> 2, seg = u & 3;      // r = tap*CB + col
      int tap = r / CB, col = r % CB;
      *(int4*)&B_lds[r * 40 + seg * 8] =
          *(const int4*)(Wtb + (size_t)tap * 65536 + (size_t)(col0 + col) * 256 + kb + seg * 8);
    }
    __syncthreads();
#pragma unroll
    for (int tap = 0; tap < 5; ++tap) {
#pragma unroll
      for (int ks = 0; ks < 2; ++ks) {
        int ko = ks * 16 + khalf * 8;
        bhalf8 a[2];
#pragma unroll
        for (int rt = 0; rt < 2; ++rt)
          a[rt] = *(const bhalf8*)&A_lds[(h * 68 + rt * 32 + l31 + tap) * 40 + ko];
#pragma unroll
        for (int ct = 0; ct < NT; ++ct) {
          bhalf8 b = *(const bhalf8*)&B_lds[(tap * CB + cpart * NT * 32 + ct * 32 + l31) * 40 + ko];
#pragma unroll
          for (int rt = 0; rt < 2; ++rt)
            acc[rt][ct] = __builtin_amdgcn_mfma_f32_32x32x16_bf16(a[rt], b, acc[rt][ct], 0, 0, 0);
        }
      }
    }
  }

#pragma unroll
  for (int rt = 0; rt < 2; ++rt) {
#pragma unroll
    for (int ct = 0; ct < NT; ++ct) {
      int c = col0 + cpart * NT * 32 + ct * 32 + l31;
      float bv = bc[c];
#pragma unroll
      for (int r = 0; r < 16; r += 2) {
        int rowg = row0 + h * 64 + rt * 32 + 4 * khalf + 8 * (r >> 2) + (r & 3);
        float y0 = fmaxf(acc[rt][ct][r] + bv, 0.f);
        float y1 = fmaxf(acc[rt][ct][r + 1] + bv, 0.f);
        float p = fmaxf(y0, y1);
        int o = rowg >> 1;
        if (OUT_F32) ((float*)Yout)[(size_t)o * 256 + c] = p;
        else ((unsigned short*)Yout)[(size_t)o * 256 + c] = f2bf(p);
      }
    }
  }
}

extern "C" void kernel_launch(void* const* d_in, const int* in_sizes, int n_in,
                              void* d_out, int out_size, void* d_ws, size_t ws_size,
                              hipStream_t stream) {
  const float* data = (const float*)d_in[0];
  const int* ei0 = (const int*)d_in[2];
  const int* ei1 = (const int*)d_in[3];
  const float* W0  = (const float*)d_in[4];
  const float* b0  = (const float*)d_in[5];
  const float* Wc0 = (const float*)d_in[6];
  const float* bc0 = (const float*)d_in[7];
  const float* W1  = (const float*)d_in[8];
  const float* b1  = (const float*)d_in[9];
  const float* Wc1 = (const float*)d_in[10];
  const float* bc1 = (const float*)d_in[11];
  float* out = (float*)d_out;

  char* base = (char*)d_ws;
  size_t off = 0;
  auto alloc = [&](size_t bytes) { void* p = base + off; off += (bytes + 255) & ~(size_t)255; return p; };
  unsigned short* X0b   = (unsigned short*)alloc((size_t)NODE0 * Ff * 2);
  unsigned short* Bm    = (unsigned short*)alloc((size_t)NODE0 * Hh * 2);
  unsigned short* P     = (unsigned short*)alloc((size_t)NODE0 * Hh * 2);
  unsigned short* X1b   = (unsigned short*)alloc((size_t)NODE0 * Hh * 2);
  unsigned short* Y0b   = (unsigned short*)alloc((size_t)NODE1 * Hh * 2);
  unsigned short* Wbot0 = (unsigned short*)alloc(256 * 128 * 2);
  unsigned short* Wd0   = (unsigned short*)alloc(256 * 128 * 2);
  unsigned short* Wbot1 = (unsigned short*)alloc(256 * 256 * 2);
  unsigned short* Wd1   = (unsigned short*)alloc(256 * 256 * 2);
  unsigned short* Wtb0  = (unsigned short*)alloc(5 * 65536 * 2);
  unsigned short* Wtb1  = (unsigned short*)alloc(5 * 65536 * 2);
  int* cnt0  = (int*)alloc(NODE0 * 4);      // cnt0+cnt1 adjacent: one memset
  int* cnt1  = (int*)alloc(NODE1 * 4);
  int* slot0 = (int*)alloc((size_t)NODE0 * CAP * 4);
  int* slot1 = (int*)alloc((size_t)NODE1 * CAP * 4);

  hipMemsetAsync(cnt0, 0, (NODE0 + NODE1) * sizeof(int), stream);

  k_prepfill<<<6528, 256, 0, stream>>>(data, X0b, W0, Wbot0, Wd0, W1, Wbot1, Wd1,
                                       Wc0, Wtb0, Wc1, Wtb1,
                                       ei0, ei1, cnt0, cnt1, slot0, slot1);

  // ---- layer 0 ----
  k_gemm2<<<dim3(NODE0 / 128, 2), 256, 0, stream>>>(X0b, Wbot0, Wd0, Bm, P, 128, b0);
  k_maxg2<<<NODE0 / 4, 256, 0, stream>>>(Bm, cnt0, slot0, P, X1b);
  k_conv32<128, 2, false><<<dim3(NODE0 / 128, 2), 256, 0, stream>>>(X1b, Wtb0, bc0, Y0b);

  // ---- layer 1 ----
  k_gemm2<<<dim3(NODE1 / 128, 2), 256, 0, stream>>>(Y0b, Wbot1, Wd1, Bm, P, 256, b1);
  k_maxg2<<<NODE1 / 4, 256, 0, stream>>>(Bm, cnt1, slot1, P, X1b);
  k_conv32<64, 2, true><<<dim3(NODE1 / 128, 2), 256, 0, stream>>>(X1b, Wtb1, bc1, out);
}